// Round 3
// baseline (542.656 us; speedup 1.0000x reference)
//
#include <hip/hip_runtime.h>
#include <hip/hip_cooperative_groups.h>
#include <math.h>

namespace cg = cooperative_groups;

#define LSEQ 4096
#define D_IN 8
#define D_MODEL 256
#define ED 512
#define NSTATE 16
#define KCONV 4
#define DT_RANK 16
#define EPS 1e-5f
#define NCHUNK 256
#define CHUNK 16   /* LSEQ / NCHUNK */

typedef short short8 __attribute__((ext_vector_type(8)));
typedef unsigned short ushort8 __attribute__((ext_vector_type(8)));
typedef float f32x4 __attribute__((ext_vector_type(4)));

__device__ __forceinline__ float sigmoidf_(float x){ return 1.f/(1.f+__expf(-x)); }
__device__ __forceinline__ float siluf_(float x){ return x*sigmoidf_(x); }
__device__ __forceinline__ float softplusf_(float x){
  return (x > 20.f) ? x : log1pf(__expf(x));
}
__device__ __forceinline__ unsigned short f2bf(float f){
  unsigned int u = __float_as_uint(f);
  return (unsigned short)((u + 0x7fffu + ((u>>16)&1u)) >> 16);
}

// ---- prep: weight bf16 conversion (blocks 0..2047) + fc_in (blocks 2048..6143) ----
__global__ void k_prep(const float* __restrict__ x, const float* __restrict__ fiw,
                       const float* __restrict__ fib, const float* __restrict__ ipw,
                       const float* __restrict__ xpw, const float* __restrict__ opw,
                       float* __restrict__ h, unsigned short* __restrict__ wip,
                       unsigned short* __restrict__ wxp, unsigned short* __restrict__ wop){
  int b = blockIdx.x, tid = threadIdx.x;
  if (b < 2048) {
    int i = b*256 + tid;                       // 0 .. 524287 == 2*1024*256
    wip[i] = f2bf(ipw[i]);
    if (i < 2*48*ED)      wxp[i] = f2bf(xpw[i]);
    if (i < 2*D_MODEL*ED) wop[i] = f2bf(opw[i]);
  } else {
    int idx = (b-2048)*256 + tid;              // t*256 + d
    int t = idx >> 8, d = idx & 255;
    float acc = fib[d];
#pragma unroll
    for (int i = 0; i < D_IN; ++i) acc += x[t*D_IN+i]*fiw[d*D_IN+i];
    h[idx] = acc;
  }
}

// ---- bf16 MFMA GEMM: C[MxN] (+)= f2bf(scale(A))[MxK] @ B[NxK]^T ----
// A fp32 (converted during staging), B pre-converted bf16.
// RMS: A'[m][k] = A[m][k] * rsqrt(mean_k A^2 + eps) * nw[k]  (requires BM=128, K mult of 32, D_MODEL=256)
template<int WM, int WN, bool RMS, bool ACC>
__global__ __launch_bounds__(256) void k_gemm_mfma(
    const float* __restrict__ A, const unsigned short* __restrict__ B,
    float* __restrict__ C, int M, int N, int K, const float* __restrict__ nwp)
{
  constexpr int BM = 32*WM, BN = 32*WN, LDT = 40;   // 32 + 8 pad (16B-aligned rows)
  __shared__ unsigned short As[BM*LDT];
  __shared__ unsigned short Bs[BN*LDT];
  __shared__ float rms_lds[BM];
  __shared__ float nws[D_MODEL];
  const int tid = threadIdx.x;
  const int bm = blockIdx.x*BM, bn = blockIdx.y*BN;
  const int w = tid >> 6, lane = tid & 63;
  const int mb = (w>>1)*WM*16, nb = (w&1)*WN*16;
  const int lr = lane & 15, lk = (lane>>4)*8;
  if (RMS) {
    nws[tid] = nwp[tid];                       // 256 threads == D_MODEL
    int row = tid >> 1, half = tid & 1;        // BM == 128
    const float* ap = A + (size_t)(bm+row)*K + half*128;
    float s = 0.f;
#pragma unroll
    for (int i = 0; i < 128; i += 4) {
      float4 v = *(const float4*)&ap[i];
      s += v.x*v.x + v.y*v.y + v.z*v.z + v.w*v.w;
    }
    s += __shfl_xor(s, 1);
    if (!half) rms_lds[row] = rsqrtf(s*(1.f/D_MODEL) + EPS);
    __syncthreads();
  }
  f32x4 acc[WM][WN] = {};
  for (int k0 = 0; k0 < K; k0 += 32) {
#pragma unroll 2
    for (int s = tid; s < BM*4; s += 256) {
      int row = s>>2, kg = (s&3)*8;
      const float* ap = &A[(size_t)(bm+row)*K + k0 + kg];
      float4 a0 = *(const float4*)ap, a1 = *(const float4*)(ap+4);
      if (RMS) {
        float rs = rms_lds[row];
        a0.x *= rs*nws[k0+kg+0]; a0.y *= rs*nws[k0+kg+1];
        a0.z *= rs*nws[k0+kg+2]; a0.w *= rs*nws[k0+kg+3];
        a1.x *= rs*nws[k0+kg+4]; a1.y *= rs*nws[k0+kg+5];
        a1.z *= rs*nws[k0+kg+6]; a1.w *= rs*nws[k0+kg+7];
      }
      ushort8 o;
      o[0]=f2bf(a0.x); o[1]=f2bf(a0.y); o[2]=f2bf(a0.z); o[3]=f2bf(a0.w);
      o[4]=f2bf(a1.x); o[5]=f2bf(a1.y); o[6]=f2bf(a1.z); o[7]=f2bf(a1.w);
      *(ushort8*)&As[row*LDT+kg] = o;
    }
#pragma unroll 2
    for (int s = tid; s < BN*4; s += 256) {
      int row = s>>2, kg = (s&3)*8;
      ushort8 v = {0,0,0,0,0,0,0,0};
      if (bn+row < N) v = *(const ushort8*)&B[(size_t)(bn+row)*K + k0 + kg];
      *(ushort8*)&Bs[row*LDT+kg] = v;
    }
    __syncthreads();
    short8 af[WM], bfr[WN];
#pragma unroll
    for (int i = 0; i < WM; ++i) af[i]  = *(const short8*)&As[(mb+i*16+lr)*LDT + lk];
#pragma unroll
    for (int j = 0; j < WN; ++j) bfr[j] = *(const short8*)&Bs[(nb+j*16+lr)*LDT + lk];
#pragma unroll
    for (int i = 0; i < WM; ++i)
#pragma unroll
      for (int j = 0; j < WN; ++j)
        acc[i][j] = __builtin_amdgcn_mfma_f32_16x16x32_bf16(af[i], bfr[j], acc[i][j], 0, 0, 0);
    __syncthreads();
  }
  // D layout: col = lane&15, row = (lane>>4)*4 + r
#pragma unroll
  for (int i = 0; i < WM; ++i) {
#pragma unroll
    for (int j = 0; j < WN; ++j) {
      int col = bn + nb + j*16 + lr;
      if (col < N) {
#pragma unroll
        for (int r = 0; r < 4; ++r) {
          int row = bm + mb + i*16 + (lane>>4)*4 + r;
          size_t o = (size_t)row*N + col;
          C[o] = ACC ? (C[o] + acc[i][j][r]) : acc[i][j][r];
        }
      }
    }
  }
}

// ---- conv + silu + x_proj fused. 16 rows/block; 256 thr = 2 cols each.
// conv writes fp32 xc to global + bf16 into the x_proj A-tile (LDS); then MFMA 16x48.
__global__ __launch_bounds__(256) void k_convxp(
    const float* __restrict__ xz, const float* __restrict__ cw, const float* __restrict__ cb,
    const unsigned short* __restrict__ wxp, float* __restrict__ xc, float* __restrict__ dbc)
{
  constexpr int BMr = 16, LDA = ED + 8;   // 520 shorts, rows 16B-aligned
  __shared__ unsigned short As[BMr*LDA];
  const int tid = threadIdx.x;
  const int t0 = blockIdx.x*BMr;
  const int e0 = tid*2;
  float c0[KCONV], c1[KCONV];
#pragma unroll
  for (int k = 0; k < KCONV; ++k) { c0[k] = cw[e0*KCONV+k]; c1[k] = cw[(e0+1)*KCONV+k]; }
  float cb0 = cb[e0], cb1 = cb[e0+1];
  float w0a=0.f,w1a=0.f,w2a=0.f, w0b=0.f,w1b=0.f,w2b=0.f;
  if (t0 > 0) {
    float2 p0 = *(const float2*)&xz[(size_t)(t0-3)*(2*ED) + e0];
    float2 p1 = *(const float2*)&xz[(size_t)(t0-2)*(2*ED) + e0];
    float2 p2 = *(const float2*)&xz[(size_t)(t0-1)*(2*ED) + e0];
    w0a=p0.x; w0b=p0.y; w1a=p1.x; w1b=p1.y; w2a=p2.x; w2b=p2.y;
  }
#pragma unroll
  for (int t = 0; t < BMr; ++t) {
    float2 cur = *(const float2*)&xz[(size_t)(t0+t)*(2*ED) + e0];
    float v0 = siluf_(cb0 + w0a*c0[0] + w1a*c0[1] + w2a*c0[2] + cur.x*c0[3]);
    float v1 = siluf_(cb1 + w0b*c1[0] + w1b*c1[1] + w2b*c1[2] + cur.y*c1[3]);
    *(float2*)&xc[(size_t)(t0+t)*ED + e0] = make_float2(v0, v1);
    unsigned int pk = (unsigned int)f2bf(v0) | ((unsigned int)f2bf(v1) << 16);
    *(unsigned int*)&As[t*LDA + e0] = pk;
    w0a=w1a; w1a=w2a; w2a=cur.x;
    w0b=w1b; w1b=w2b; w2b=cur.y;
  }
  __syncthreads();
  // x_proj: dbc[16 x 48] = A[16 x 512] @ wxp[48 x 512]^T ; waves 0..2 take col-tiles
  const int w = tid >> 6, lane = tid & 63;
  const int lr = lane & 15, lk = (lane>>4)*8;
  if (w < 3) {
    f32x4 acc = {};
#pragma unroll
    for (int ks = 0; ks < ED/32; ++ks) {
      short8 af = *(const short8*)&As[lr*LDA + ks*32 + lk];
      short8 bf = *(const short8*)&wxp[(size_t)(w*16+lr)*ED + ks*32 + lk];
      acc = __builtin_amdgcn_mfma_f32_16x16x32_bf16(af, bf, acc, 0, 0, 0);
    }
#pragma unroll
    for (int r = 0; r < 4; ++r)
      dbc[(size_t)(t0 + (lane>>4)*4 + r)*48 + w*16 + lr] = acc[r];
  }
}

// ---- cooperative fused scan: phase1 (dt_proj + local scan) / phase2 (chunk combine)
// / phase3 (replay + C-dot + D-skip + silu(z) gate), registers persist across phases.
__global__ __launch_bounds__(256, 2) void k_scan_coop(
    const float* __restrict__ xc, const float* __restrict__ dbc,
    const float* __restrict__ dtw, const float* __restrict__ dtb,
    const float* __restrict__ alog, const float* __restrict__ xz,
    const float* __restrict__ Dv, float* __restrict__ S,
    float* __restrict__ Q, float* __restrict__ y)
{
  cg::grid_group grid = cg::this_grid();
  __shared__ float Ds[CHUNK][DT_RANK];
  __shared__ float Bsh[CHUNK][NSTATE];
  __shared__ float Cs[CHUNK][NSTATE];
  const int tid = threadIdx.x;
  const int c = blockIdx.x >> 1;
  const int e = (blockIdx.x & 1)*256 + tid;
  const int t0 = c*CHUNK;
  for (int i = tid; i < CHUNK*48; i += 256) {
    int t = i/48, col = i - t*48;
    float v = dbc[(size_t)(t0+t)*48 + col];
    if (col < DT_RANK) Ds[t][col] = v;
    else if (col < DT_RANK+NSTATE) Bsh[t][col-DT_RANK] = v;
    else Cs[t][col-DT_RANK-NSTATE] = v;
  }
  __syncthreads();
  float x[CHUNK], z[CHUNK], dl[CHUNK], A[NSTATE], h[NSTATE];
  {
    float dtwv[DT_RANK];
#pragma unroll
    for (int r = 0; r < DT_RANK; ++r) dtwv[r] = dtw[e*DT_RANK+r];
    float dtbv = dtb[e];
#pragma unroll
    for (int t = 0; t < CHUNK; ++t) {
      float da = dtbv;
#pragma unroll
      for (int r = 0; r < DT_RANK; ++r) da += Ds[t][r]*dtwv[r];
      dl[t] = softplusf_(da);
    }
  }
#pragma unroll
  for (int t = 0; t < CHUNK; ++t) x[t] = xc[(size_t)(t0+t)*ED + e];
#pragma unroll
  for (int t = 0; t < CHUNK; ++t) z[t] = xz[(size_t)(t0+t)*(2*ED) + ED + e];
#pragma unroll
  for (int n = 0; n < NSTATE; ++n) { A[n] = -__expf(alog[e*NSTATE+n]); h[n] = 0.f; }
  float sd = 0.f;
#pragma unroll
  for (int t = 0; t < CHUNK; ++t) {
    sd += dl[t];
    float dx = dl[t]*x[t];
#pragma unroll
    for (int n = 0; n < NSTATE; ++n)
      h[n] = __expf(dl[t]*A[n])*h[n] + dx*Bsh[t][n];
  }
  S[c*ED + e] = sd;
#pragma unroll
  for (int n = 0; n < NSTATE; ++n) Q[(size_t)(c*NSTATE+n)*ED + e] = h[n];

  grid.sync();

  if (blockIdx.x < 32) {   // 8192 channels: chunk-combine, in-place Q -> Hin
    int ch = blockIdx.x*256 + tid;
    int n2 = ch >> 9, e2 = ch & 511;
    float a = -__expf(alog[e2*NSTATE+n2]);
    float hh = 0.f;
    for (int g = 0; g < NCHUNK/8; ++g) {
      float sv[8], qv[8];
#pragma unroll
      for (int k = 0; k < 8; ++k) sv[k] = S[(size_t)(g*8+k)*ED + e2];
#pragma unroll
      for (int k = 0; k < 8; ++k) qv[k] = Q[(size_t)((g*8+k)*NSTATE+n2)*ED + e2];
#pragma unroll
      for (int k = 0; k < 8; ++k) sv[k] = __expf(a*sv[k]);
#pragma unroll
      for (int k = 0; k < 8; ++k) {
        Q[(size_t)((g*8+k)*NSTATE+n2)*ED + e2] = hh;
        hh = sv[k]*hh + qv[k];
      }
    }
  }

  grid.sync();

#pragma unroll
  for (int n = 0; n < NSTATE; ++n) h[n] = Q[(size_t)(c*NSTATE+n)*ED + e];
  float dv = Dv[e];
#pragma unroll
  for (int t = 0; t < CHUNK; ++t) {
    float dx = dl[t]*x[t];
    float ysum = 0.f;
#pragma unroll
    for (int n = 0; n < NSTATE; ++n) {
      h[n] = __expf(dl[t]*A[n])*h[n] + dx*Bsh[t][n];
      ysum += h[n]*Cs[t][n];
    }
    y[(size_t)(t0+t)*ED + e] = (ysum + dv*x[t]) * siluf_(z[t]);
  }
}

// out[t] = tanh( h[t][:] . fc_out_w + fc_out_b ) — one wave per row
__global__ void k_fc_out(const float* __restrict__ h, const float* __restrict__ w,
                         const float* __restrict__ b, float* __restrict__ out){
  int wave = threadIdx.x >> 6, lane = threadIdx.x & 63;
  int row = blockIdx.x*4 + wave;
  const float4 hv = *(const float4*)&h[row*D_MODEL + lane*4];
  const float4 wv = *(const float4*)&w[lane*4];
  float s = hv.x*wv.x + hv.y*wv.y + hv.z*wv.z + hv.w*wv.w;
#pragma unroll
  for (int m = 32; m; m >>= 1) s += __shfl_xor(s, m);
  if (lane == 0) out[row] = tanhf(s + b[0]);
}

extern "C" void kernel_launch(void* const* d_in, const int* in_sizes, int n_in,
                              void* d_out, int out_size, void* d_ws, size_t ws_size,
                              hipStream_t stream){
  const float* x    = (const float*)d_in[0];
  const float* fiw  = (const float*)d_in[1];
  const float* fib  = (const float*)d_in[2];
  const float* fow  = (const float*)d_in[3];
  const float* fob  = (const float*)d_in[4];
  const float* nw   = (const float*)d_in[5];
  const float* ipw  = (const float*)d_in[6];
  const float* cw   = (const float*)d_in[7];
  const float* cb   = (const float*)d_in[8];
  const float* xpw  = (const float*)d_in[9];
  const float* dtw  = (const float*)d_in[10];
  const float* dtb  = (const float*)d_in[11];
  const float* alog = (const float*)d_in[12];
  const float* Dv   = (const float*)d_in[13];
  const float* opw  = (const float*)d_in[14];

  float* W = (float*)d_ws;
  float* h   = W;                                   // L*256
  float* xz  = h   + (size_t)LSEQ*D_MODEL;          // L*1024
  float* xc  = xz  + (size_t)LSEQ*2*ED;             // L*512
  float* dbc = xc  + (size_t)LSEQ*ED;               // L*48
  float* S   = dbc + (size_t)LSEQ*48;               // 256*512
  float* Q   = S   + (size_t)NCHUNK*ED;             // 256*16*512 (Hin in-place)
  float* yf  = Q   + (size_t)NCHUNK*NSTATE*ED;      // L*512
  unsigned short* wip = (unsigned short*)(yf + (size_t)LSEQ*ED); // 2*1024*256
  unsigned short* wxp = wip + (size_t)2*2*ED*D_MODEL;            // 2*48*512
  unsigned short* wop = wxp + (size_t)2*48*ED;                   // 2*256*512

  k_prep<<<2048 + LSEQ, 256, 0, stream>>>(x, fiw, fib, ipw, xpw, opw, h, wip, wxp, wop);

  for (int l = 0; l < 2; ++l) {
    const unsigned short* wip_l = wip + (size_t)l*2*ED*D_MODEL;
    const unsigned short* wxp_l = wxp + (size_t)l*48*ED;
    const unsigned short* wop_l = wop + (size_t)l*D_MODEL*ED;
    const float* nw_l   = nw   + l*D_MODEL;
    const float* cw_l   = cw   + l*ED*KCONV;
    const float* cb_l   = cb   + l*ED;
    const float* dtw_l  = dtw  + l*ED*DT_RANK;
    const float* dtb_l  = dtb  + l*ED;
    const float* alog_l = alog + l*ED*NSTATE;
    const float* D_l    = Dv   + l*ED;

    k_gemm_mfma<4,4,true,false><<<dim3(LSEQ/128, (2*ED)/128), 256, 0, stream>>>(
        h, wip_l, xz, LSEQ, 2*ED, D_MODEL, nw_l);
    k_convxp<<<LSEQ/16, 256, 0, stream>>>(xz, cw_l, cb_l, wxp_l, xc, dbc);
    {
      void* kargs[10] = {
        (void*)&xc, (void*)&dbc, (void*)&dtw_l, (void*)&dtb_l, (void*)&alog_l,
        (void*)&xz, (void*)&D_l, (void*)&S, (void*)&Q, (void*)&yf
      };
      hipLaunchCooperativeKernel((void*)k_scan_coop, dim3(NCHUNK*2), dim3(256),
                                 kargs, 0, stream);
    }
    k_gemm_mfma<2,2,false,true><<<dim3(LSEQ/64, D_MODEL/64), 256, 0, stream>>>(
        yf, wop_l, h, LSEQ, D_MODEL, ED, nullptr);
  }

  k_fc_out<<<LSEQ/4, 256, 0, stream>>>(h, fow, fob, (float*)d_out);
}

// Round 4
// 224.829 us; speedup vs baseline: 2.4136x; 2.4136x over previous
//
#include <hip/hip_runtime.h>
#include <math.h>

#define LSEQ 4096
#define D_IN 8
#define D_MODEL 256
#define ED 512
#define NSTATE 16
#define KCONV 4
#define DT_RANK 16
#define EPS 1e-5f
#define NCHUNK 256
#define CHUNK 16   /* LSEQ / NCHUNK */

typedef short short8 __attribute__((ext_vector_type(8)));
typedef unsigned short ushort8 __attribute__((ext_vector_type(8)));
typedef float f32x4 __attribute__((ext_vector_type(4)));

__device__ __forceinline__ float sigmoidf_(float x){ return 1.f/(1.f+__expf(-x)); }
__device__ __forceinline__ float siluf_(float x){ return x*sigmoidf_(x); }
__device__ __forceinline__ float softplusf_(float x){
  return (x > 20.f) ? x : log1pf(__expf(x));
}
__device__ __forceinline__ unsigned short f2bf(float f){
  unsigned int u = __float_as_uint(f);
  return (unsigned short)((u + 0x7fffu + ((u>>16)&1u)) >> 16);
}

// ---- prep: weight bf16 conversion (blocks 0..2047) + fc_in (blocks 2048..6143) ----
__global__ void k_prep(const float* __restrict__ x, const float* __restrict__ fiw,
                       const float* __restrict__ fib, const float* __restrict__ ipw,
                       const float* __restrict__ xpw, const float* __restrict__ opw,
                       float* __restrict__ h, unsigned short* __restrict__ wip,
                       unsigned short* __restrict__ wxp, unsigned short* __restrict__ wop){
  int b = blockIdx.x, tid = threadIdx.x;
  if (b < 2048) {
    int i = b*256 + tid;                       // 0 .. 524287 == 2*1024*256
    wip[i] = f2bf(ipw[i]);
    if (i < 2*48*ED)      wxp[i] = f2bf(xpw[i]);
    if (i < 2*D_MODEL*ED) wop[i] = f2bf(opw[i]);
  } else {
    int idx = (b-2048)*256 + tid;              // t*256 + d
    int t = idx >> 8, d = idx & 255;
    float acc = fib[d];
#pragma unroll
    for (int i = 0; i < D_IN; ++i) acc += x[t*D_IN+i]*fiw[d*D_IN+i];
    h[idx] = acc;
  }
}

// ---- bf16 MFMA GEMM: C[MxN] (+)= f2bf(scale(A))[MxK] @ B[NxK]^T ----
// A fp32 (converted during staging), B pre-converted bf16.
// RMS: A'[m][k] = A[m][k] * rsqrt(mean_k A^2 + eps) * nw[k]  (BM=128, K=D_MODEL=256)
template<int WM, int WN, bool RMS, bool ACC>
__global__ __launch_bounds__(256) void k_gemm_mfma(
    const float* __restrict__ A, const unsigned short* __restrict__ B,
    float* __restrict__ C, int M, int N, int K, const float* __restrict__ nwp)
{
  constexpr int BM = 32*WM, BN = 32*WN, LDT = 40;   // 32 + 8 pad (16B-aligned rows)
  __shared__ unsigned short As[BM*LDT];
  __shared__ unsigned short Bs[BN*LDT];
  __shared__ float rms_lds[BM];
  __shared__ float nws[D_MODEL];
  const int tid = threadIdx.x;
  const int bm = blockIdx.x*BM, bn = blockIdx.y*BN;
  const int w = tid >> 6, lane = tid & 63;
  const int mb = (w>>1)*WM*16, nb = (w&1)*WN*16;
  const int lr = lane & 15, lk = (lane>>4)*8;
  if (RMS) {
    nws[tid] = nwp[tid];                       // 256 threads == D_MODEL
    int row = tid >> 1, half = tid & 1;        // BM == 128
    const float* ap = A + (size_t)(bm+row)*K + half*128;
    float s = 0.f;
#pragma unroll
    for (int i = 0; i < 128; i += 4) {
      float4 v = *(const float4*)&ap[i];
      s += v.x*v.x + v.y*v.y + v.z*v.z + v.w*v.w;
    }
    s += __shfl_xor(s, 1);
    if (!half) rms_lds[row] = rsqrtf(s*(1.f/D_MODEL) + EPS);
    __syncthreads();
  }
  f32x4 acc[WM][WN] = {};
  for (int k0 = 0; k0 < K; k0 += 32) {
#pragma unroll 2
    for (int s = tid; s < BM*4; s += 256) {
      int row = s>>2, kg = (s&3)*8;
      const float* ap = &A[(size_t)(bm+row)*K + k0 + kg];
      float4 a0 = *(const float4*)ap, a1 = *(const float4*)(ap+4);
      if (RMS) {
        float rs = rms_lds[row];
        a0.x *= rs*nws[k0+kg+0]; a0.y *= rs*nws[k0+kg+1];
        a0.z *= rs*nws[k0+kg+2]; a0.w *= rs*nws[k0+kg+3];
        a1.x *= rs*nws[k0+kg+4]; a1.y *= rs*nws[k0+kg+5];
        a1.z *= rs*nws[k0+kg+6]; a1.w *= rs*nws[k0+kg+7];
      }
      ushort8 o;
      o[0]=f2bf(a0.x); o[1]=f2bf(a0.y); o[2]=f2bf(a0.z); o[3]=f2bf(a0.w);
      o[4]=f2bf(a1.x); o[5]=f2bf(a1.y); o[6]=f2bf(a1.z); o[7]=f2bf(a1.w);
      *(ushort8*)&As[row*LDT+kg] = o;
    }
#pragma unroll 2
    for (int s = tid; s < BN*4; s += 256) {
      int row = s>>2, kg = (s&3)*8;
      ushort8 v = {0,0,0,0,0,0,0,0};
      if (bn+row < N) v = *(const ushort8*)&B[(size_t)(bn+row)*K + k0 + kg];
      *(ushort8*)&Bs[row*LDT+kg] = v;
    }
    __syncthreads();
    short8 af[WM], bfr[WN];
#pragma unroll
    for (int i = 0; i < WM; ++i) af[i]  = *(const short8*)&As[(mb+i*16+lr)*LDT + lk];
#pragma unroll
    for (int j = 0; j < WN; ++j) bfr[j] = *(const short8*)&Bs[(nb+j*16+lr)*LDT + lk];
#pragma unroll
    for (int i = 0; i < WM; ++i)
#pragma unroll
      for (int j = 0; j < WN; ++j)
        acc[i][j] = __builtin_amdgcn_mfma_f32_16x16x32_bf16(af[i], bfr[j], acc[i][j], 0, 0, 0);
    __syncthreads();
  }
  // D layout: col = lane&15, row = (lane>>4)*4 + r
#pragma unroll
  for (int i = 0; i < WM; ++i) {
#pragma unroll
    for (int j = 0; j < WN; ++j) {
      int col = bn + nb + j*16 + lr;
      if (col < N) {
#pragma unroll
        for (int r = 0; r < 4; ++r) {
          int row = bm + mb + i*16 + (lane>>4)*4 + r;
          size_t o = (size_t)row*N + col;
          C[o] = ACC ? (C[o] + acc[i][j][r]) : acc[i][j][r];
        }
      }
    }
  }
}

// ---- conv + silu + x_proj fused. 16 rows/block; 256 thr = 2 cols each.
__global__ __launch_bounds__(256) void k_convxp(
    const float* __restrict__ xz, const float* __restrict__ cw, const float* __restrict__ cb,
    const unsigned short* __restrict__ wxp, float* __restrict__ xc, float* __restrict__ dbc)
{
  constexpr int BMr = 16, LDA = ED + 8;   // 520 shorts, rows 16B-aligned
  __shared__ unsigned short As[BMr*LDA];
  const int tid = threadIdx.x;
  const int t0 = blockIdx.x*BMr;
  const int e0 = tid*2;
  float c0[KCONV], c1[KCONV];
#pragma unroll
  for (int k = 0; k < KCONV; ++k) { c0[k] = cw[e0*KCONV+k]; c1[k] = cw[(e0+1)*KCONV+k]; }
  float cb0 = cb[e0], cb1 = cb[e0+1];
  float w0a=0.f,w1a=0.f,w2a=0.f, w0b=0.f,w1b=0.f,w2b=0.f;
  if (t0 > 0) {
    float2 p0 = *(const float2*)&xz[(size_t)(t0-3)*(2*ED) + e0];
    float2 p1 = *(const float2*)&xz[(size_t)(t0-2)*(2*ED) + e0];
    float2 p2 = *(const float2*)&xz[(size_t)(t0-1)*(2*ED) + e0];
    w0a=p0.x; w0b=p0.y; w1a=p1.x; w1b=p1.y; w2a=p2.x; w2b=p2.y;
  }
#pragma unroll
  for (int t = 0; t < BMr; ++t) {
    float2 cur = *(const float2*)&xz[(size_t)(t0+t)*(2*ED) + e0];
    float v0 = siluf_(cb0 + w0a*c0[0] + w1a*c0[1] + w2a*c0[2] + cur.x*c0[3]);
    float v1 = siluf_(cb1 + w0b*c1[0] + w1b*c1[1] + w2b*c1[2] + cur.y*c1[3]);
    *(float2*)&xc[(size_t)(t0+t)*ED + e0] = make_float2(v0, v1);
    unsigned int pk = (unsigned int)f2bf(v0) | ((unsigned int)f2bf(v1) << 16);
    *(unsigned int*)&As[t*LDA + e0] = pk;
    w0a=w1a; w1a=w2a; w2a=cur.x;
    w0b=w1b; w1b=w2b; w2b=cur.y;
  }
  __syncthreads();
  // x_proj: dbc[16 x 48] = A[16 x 512] @ wxp[48 x 512]^T ; waves 0..2 take col-tiles
  const int w = tid >> 6, lane = tid & 63;
  const int lr = lane & 15, lk = (lane>>4)*8;
  if (w < 3) {
    f32x4 acc = {};
#pragma unroll
    for (int ks = 0; ks < ED/32; ++ks) {
      short8 af = *(const short8*)&As[lr*LDA + ks*32 + lk];
      short8 bf = *(const short8*)&wxp[(size_t)(w*16+lr)*ED + ks*32 + lk];
      acc = __builtin_amdgcn_mfma_f32_16x16x32_bf16(af, bf, acc, 0, 0, 0);
    }
#pragma unroll
    for (int r = 0; r < 4; ++r)
      dbc[(size_t)(t0 + (lane>>4)*4 + r)*48 + w*16 + lr] = acc[r];
  }
}

// Phase 1 (dt_proj fused): per chunk c, per e: S = sum delta; Q = local scan end (h0=0)
__global__ __launch_bounds__(256) void k_scan1(
    const float* __restrict__ xc, const float* __restrict__ dbc,
    const float* __restrict__ dtw, const float* __restrict__ dtb,
    const float* __restrict__ alog, float* __restrict__ S, float* __restrict__ Q){
  __shared__ float Ds[CHUNK][DT_RANK];
  __shared__ float Bsh[CHUNK][NSTATE];
  int c = blockIdx.x >> 1;
  int e = (blockIdx.x & 1)*256 + threadIdx.x;
  int t0 = c*CHUNK;
  for (int i = threadIdx.x; i < CHUNK*48; i += 256) {
    int t = i/48, col = i - t*48;
    float v = dbc[(size_t)(t0+t)*48 + col];
    if (col < DT_RANK) Ds[t][col] = v;
    else if (col < DT_RANK+NSTATE) Bsh[t][col-DT_RANK] = v;
  }
  __syncthreads();
  float dtwv[DT_RANK];
#pragma unroll
  for (int r = 0; r < DT_RANK; ++r) dtwv[r] = dtw[e*DT_RANK+r];
  float dtbv = dtb[e];
  float x[CHUNK];
#pragma unroll
  for (int t = 0; t < CHUNK; ++t) x[t] = xc[(size_t)(t0+t)*ED + e];
  float A[NSTATE];
#pragma unroll
  for (int n = 0; n < NSTATE; ++n) A[n] = -__expf(alog[e*NSTATE+n]);
  float h[NSTATE] = {};
  float sd = 0.f;
#pragma unroll
  for (int t = 0; t < CHUNK; ++t) {
    float da = dtbv;
#pragma unroll
    for (int r = 0; r < DT_RANK; ++r) da += Ds[t][r]*dtwv[r];
    float d = softplusf_(da);
    sd += d;
    float dx = d*x[t];
#pragma unroll
    for (int n = 0; n < NSTATE; ++n)
      h[n] = __expf(d*A[n])*h[n] + dx*Bsh[t][n];
  }
  S[c*ED + e] = sd;
#pragma unroll
  for (int n = 0; n < NSTATE; ++n) Q[(size_t)(c*NSTATE+n)*ED + e] = h[n];
}

// Phase 2: sequential over 256 chunks, parallel over 8192 (n,e) channels.
// In-place: Q[c] (local end state) is replaced by Hin[c] (true state BEFORE chunk c).
__global__ void k_scan2(const float* __restrict__ alog, const float* __restrict__ S,
                        float* __restrict__ Q){
  int ch = blockIdx.x*256 + threadIdx.x;  // n*512 + e
  int n = ch >> 9, e = ch & 511;
  float a = -__expf(alog[e*NSTATE+n]);
  float h = 0.f;
  for (int g = 0; g < NCHUNK/8; ++g) {
    float sv[8], qv[8];
#pragma unroll
    for (int k = 0; k < 8; ++k) sv[k] = S[(size_t)(g*8+k)*ED + e];
#pragma unroll
    for (int k = 0; k < 8; ++k) qv[k] = Q[(size_t)((g*8+k)*NSTATE+n)*ED + e];
#pragma unroll
    for (int k = 0; k < 8; ++k) sv[k] = __expf(a*sv[k]);
#pragma unroll
    for (int k = 0; k < 8; ++k) {
      Q[(size_t)((g*8+k)*NSTATE+n)*ED + e] = h;
      h = sv[k]*h + qv[k];
    }
  }
}

// Phase 3: replay chunk with true Hin; fuse dt_proj, C-dot, D-skip, silu(z) gate.
__global__ __launch_bounds__(256) void k_scan3(
    const float* __restrict__ xc, const float* __restrict__ dbc,
    const float* __restrict__ dtw, const float* __restrict__ dtb,
    const float* __restrict__ alog, const float* __restrict__ Hin,
    const float* __restrict__ xz, const float* __restrict__ Dv,
    float* __restrict__ y){
  __shared__ float Ds[CHUNK][DT_RANK];
  __shared__ float Bsh[CHUNK][NSTATE];
  __shared__ float Cs[CHUNK][NSTATE];
  int c = blockIdx.x >> 1;
  int e = (blockIdx.x & 1)*256 + threadIdx.x;
  int t0 = c*CHUNK;
  for (int i = threadIdx.x; i < CHUNK*48; i += 256) {
    int t = i/48, col = i - t*48;
    float v = dbc[(size_t)(t0+t)*48 + col];
    if (col < DT_RANK) Ds[t][col] = v;
    else if (col < DT_RANK+NSTATE) Bsh[t][col-DT_RANK] = v;
    else Cs[t][col-DT_RANK-NSTATE] = v;
  }
  __syncthreads();
  float dtwv[DT_RANK];
#pragma unroll
  for (int r = 0; r < DT_RANK; ++r) dtwv[r] = dtw[e*DT_RANK+r];
  float dtbv = dtb[e];
  float x[CHUNK], z[CHUNK];
#pragma unroll
  for (int t = 0; t < CHUNK; ++t) x[t] = xc[(size_t)(t0+t)*ED + e];
#pragma unroll
  for (int t = 0; t < CHUNK; ++t) z[t] = xz[(size_t)(t0+t)*(2*ED) + ED + e];
  float A[NSTATE], h[NSTATE];
#pragma unroll
  for (int n = 0; n < NSTATE; ++n) {
    A[n] = -__expf(alog[e*NSTATE+n]);
    h[n] = Hin[(size_t)(c*NSTATE+n)*ED + e];
  }
  float dv = Dv[e];
#pragma unroll
  for (int t = 0; t < CHUNK; ++t) {
    float da = dtbv;
#pragma unroll
    for (int r = 0; r < DT_RANK; ++r) da += Ds[t][r]*dtwv[r];
    float d = softplusf_(da);
    float dx = d*x[t];
    float ysum = 0.f;
#pragma unroll
    for (int n = 0; n < NSTATE; ++n) {
      h[n] = __expf(d*A[n])*h[n] + dx*Bsh[t][n];
      ysum += h[n]*Cs[t][n];
    }
    y[(size_t)(t0+t)*ED + e] = (ysum + dv*x[t]) * siluf_(z[t]);
  }
}

// out[t] = tanh( h[t][:] . fc_out_w + fc_out_b ) — one wave per row
__global__ void k_fc_out(const float* __restrict__ h, const float* __restrict__ w,
                         const float* __restrict__ b, float* __restrict__ out){
  int wave = threadIdx.x >> 6, lane = threadIdx.x & 63;
  int row = blockIdx.x*4 + wave;
  const float4 hv = *(const float4*)&h[row*D_MODEL + lane*4];
  const float4 wv = *(const float4*)&w[lane*4];
  float s = hv.x*wv.x + hv.y*wv.y + hv.z*wv.z + hv.w*wv.w;
#pragma unroll
  for (int m = 32; m; m >>= 1) s += __shfl_xor(s, m);
  if (lane == 0) out[row] = tanhf(s + b[0]);
}

extern "C" void kernel_launch(void* const* d_in, const int* in_sizes, int n_in,
                              void* d_out, int out_size, void* d_ws, size_t ws_size,
                              hipStream_t stream){
  const float* x    = (const float*)d_in[0];
  const float* fiw  = (const float*)d_in[1];
  const float* fib  = (const float*)d_in[2];
  const float* fow  = (const float*)d_in[3];
  const float* fob  = (const float*)d_in[4];
  const float* nw   = (const float*)d_in[5];
  const float* ipw  = (const float*)d_in[6];
  const float* cw   = (const float*)d_in[7];
  const float* cb   = (const float*)d_in[8];
  const float* xpw  = (const float*)d_in[9];
  const float* dtw  = (const float*)d_in[10];
  const float* dtb  = (const float*)d_in[11];
  const float* alog = (const float*)d_in[12];
  const float* Dv   = (const float*)d_in[13];
  const float* opw  = (const float*)d_in[14];

  float* W = (float*)d_ws;
  float* h   = W;                                   // L*256
  float* xz  = h   + (size_t)LSEQ*D_MODEL;          // L*1024
  float* xc  = xz  + (size_t)LSEQ*2*ED;             // L*512
  float* dbc = xc  + (size_t)LSEQ*ED;               // L*48
  float* S   = dbc + (size_t)LSEQ*48;               // 256*512
  float* Q   = S   + (size_t)NCHUNK*ED;             // 256*16*512 (Hin in-place)
  float* yf  = Q   + (size_t)NCHUNK*NSTATE*ED;      // L*512
  unsigned short* wip = (unsigned short*)(yf + (size_t)LSEQ*ED); // 2*1024*256
  unsigned short* wxp = wip + (size_t)2*2*ED*D_MODEL;            // 2*48*512
  unsigned short* wop = wxp + (size_t)2*48*ED;                   // 2*256*512

  k_prep<<<2048 + LSEQ, 256, 0, stream>>>(x, fiw, fib, ipw, xpw, opw, h, wip, wxp, wop);

  for (int l = 0; l < 2; ++l) {
    const unsigned short* wip_l = wip + (size_t)l*2*ED*D_MODEL;
    const unsigned short* wxp_l = wxp + (size_t)l*48*ED;
    const unsigned short* wop_l = wop + (size_t)l*D_MODEL*ED;
    const float* nw_l   = nw   + l*D_MODEL;
    const float* cw_l   = cw   + l*ED*KCONV;
    const float* cb_l   = cb   + l*ED;
    const float* dtw_l  = dtw  + l*ED*DT_RANK;
    const float* dtb_l  = dtb  + l*ED;
    const float* alog_l = alog + l*ED*NSTATE;
    const float* D_l    = Dv   + l*ED;

    k_gemm_mfma<4,4,true,false><<<dim3(LSEQ/128, (2*ED)/128), 256, 0, stream>>>(
        h, wip_l, xz, LSEQ, 2*ED, D_MODEL, nw_l);
    k_convxp<<<LSEQ/16, 256, 0, stream>>>(xz, cw_l, cb_l, wxp_l, xc, dbc);
    k_scan1<<<NCHUNK*2, 256, 0, stream>>>(xc, dbc, dtw_l, dtb_l, alog_l, S, Q);
    k_scan2<<<ED*NSTATE/256, 256, 0, stream>>>(alog_l, S, Q);
    k_scan3<<<NCHUNK*2, 256, 0, stream>>>(xc, dbc, dtw_l, dtb_l, alog_l, Q, xz, D_l, yf);
    k_gemm_mfma<2,2,false,true><<<dim3(LSEQ/64, D_MODEL/64), 256, 0, stream>>>(
        yf, wop_l, h, LSEQ, D_MODEL, ED, nullptr);
  }

  k_fc_out<<<LSEQ/4, 256, 0, stream>>>(h, fow, fob, (float*)d_out);
}

// Round 5
// 184.889 us; speedup vs baseline: 2.9350x; 1.2160x over previous
//
#include <hip/hip_runtime.h>
#include <math.h>

#define LSEQ 4096
#define D_IN 8
#define D_MODEL 256
#define ED 512
#define NSTATE 16
#define KCONV 4
#define DT_RANK 16
#define EPS 1e-5f
#define NCHUNK 256
#define CHUNK 16   /* LSEQ / NCHUNK */

typedef short short8 __attribute__((ext_vector_type(8)));
typedef unsigned short ushort8 __attribute__((ext_vector_type(8)));
typedef float f32x4 __attribute__((ext_vector_type(4)));

__device__ __forceinline__ float sigmoidf_(float x){ return 1.f/(1.f+__expf(-x)); }
__device__ __forceinline__ float siluf_(float x){ return x*sigmoidf_(x); }
__device__ __forceinline__ float softplusf_(float x){
  return (x > 20.f) ? x : log1pf(__expf(x));
}
__device__ __forceinline__ unsigned short f2bf(float f){
  unsigned int u = __float_as_uint(f);
  return (unsigned short)((u + 0x7fffu + ((u>>16)&1u)) >> 16);
}

// ---- prep: weight bf16 conversion (blocks 0..2047) + fc_in (blocks 2048..6143) ----
__global__ void k_prep(const float* __restrict__ x, const float* __restrict__ fiw,
                       const float* __restrict__ fib, const float* __restrict__ ipw,
                       const float* __restrict__ xpw, const float* __restrict__ opw,
                       float* __restrict__ h, unsigned short* __restrict__ wip,
                       unsigned short* __restrict__ wxp, unsigned short* __restrict__ wop){
  int b = blockIdx.x, tid = threadIdx.x;
  if (b < 2048) {
    int i = b*256 + tid;                       // 0 .. 524287 == 2*1024*256
    wip[i] = f2bf(ipw[i]);
    if (i < 2*48*ED)      wxp[i] = f2bf(xpw[i]);
    if (i < 2*D_MODEL*ED) wop[i] = f2bf(opw[i]);
  } else {
    int idx = (b-2048)*256 + tid;              // t*256 + d
    int t = idx >> 8, d = idx & 255;
    float acc = fib[d];
#pragma unroll
    for (int i = 0; i < D_IN; ++i) acc += x[t*D_IN+i]*fiw[d*D_IN+i];
    h[idx] = acc;
  }
}

// ---- bf16 MFMA GEMM: C[MxN] (+)= A[MxK] @ B[NxK]^T ----
// ABF16: A already bf16.  Else A fp32, converted during staging; RMS optionally fused.
template<int WM, int WN, bool RMS, bool ACC, bool ABF16>
__global__ __launch_bounds__(256) void k_gemm_mfma(
    const void* __restrict__ Ap, const unsigned short* __restrict__ B,
    float* __restrict__ C, int M, int N, int K, const float* __restrict__ nwp)
{
  constexpr int BM = 32*WM, BN = 32*WN, LDT = 40;   // 32 + 8 pad (16B-aligned rows)
  const float* A = (const float*)Ap;
  const unsigned short* Ab = (const unsigned short*)Ap;
  __shared__ unsigned short As[BM*LDT];
  __shared__ unsigned short Bs[BN*LDT];
  __shared__ float rms_lds[BM];
  __shared__ float nws[D_MODEL];
  const int tid = threadIdx.x;
  const int bm = blockIdx.x*BM, bn = blockIdx.y*BN;
  const int w = tid >> 6, lane = tid & 63;
  const int mb = (w>>1)*WM*16, nb = (w&1)*WN*16;
  const int lr = lane & 15, lk = (lane>>4)*8;
  if (RMS) {
    nws[tid] = nwp[tid];                       // 256 threads == D_MODEL
    int row = tid >> 1, half = tid & 1;        // BM == 128
    const float* ap = A + (size_t)(bm+row)*K + half*128;
    float s = 0.f;
#pragma unroll
    for (int i = 0; i < 128; i += 4) {
      float4 v = *(const float4*)&ap[i];
      s += v.x*v.x + v.y*v.y + v.z*v.z + v.w*v.w;
    }
    s += __shfl_xor(s, 1);
    if (!half) rms_lds[row] = rsqrtf(s*(1.f/D_MODEL) + EPS);
    __syncthreads();
  }
  f32x4 acc[WM][WN] = {};
  for (int k0 = 0; k0 < K; k0 += 32) {
#pragma unroll 2
    for (int s = tid; s < BM*4; s += 256) {
      int row = s>>2, kg = (s&3)*8;
      if (ABF16) {
        *(ushort8*)&As[row*LDT+kg] = *(const ushort8*)&Ab[(size_t)(bm+row)*K + k0 + kg];
      } else {
        const float* ap = &A[(size_t)(bm+row)*K + k0 + kg];
        float4 a0 = *(const float4*)ap, a1 = *(const float4*)(ap+4);
        if (RMS) {
          float rs = rms_lds[row];
          a0.x *= rs*nws[k0+kg+0]; a0.y *= rs*nws[k0+kg+1];
          a0.z *= rs*nws[k0+kg+2]; a0.w *= rs*nws[k0+kg+3];
          a1.x *= rs*nws[k0+kg+4]; a1.y *= rs*nws[k0+kg+5];
          a1.z *= rs*nws[k0+kg+6]; a1.w *= rs*nws[k0+kg+7];
        }
        ushort8 o;
        o[0]=f2bf(a0.x); o[1]=f2bf(a0.y); o[2]=f2bf(a0.z); o[3]=f2bf(a0.w);
        o[4]=f2bf(a1.x); o[5]=f2bf(a1.y); o[6]=f2bf(a1.z); o[7]=f2bf(a1.w);
        *(ushort8*)&As[row*LDT+kg] = o;
      }
    }
#pragma unroll 2
    for (int s = tid; s < BN*4; s += 256) {
      int row = s>>2, kg = (s&3)*8;
      ushort8 v = {0,0,0,0,0,0,0,0};
      if (bn+row < N) v = *(const ushort8*)&B[(size_t)(bn+row)*K + k0 + kg];
      *(ushort8*)&Bs[row*LDT+kg] = v;
    }
    __syncthreads();
    short8 af[WM], bfr[WN];
#pragma unroll
    for (int i = 0; i < WM; ++i) af[i]  = *(const short8*)&As[(mb+i*16+lr)*LDT + lk];
#pragma unroll
    for (int j = 0; j < WN; ++j) bfr[j] = *(const short8*)&Bs[(nb+j*16+lr)*LDT + lk];
#pragma unroll
    for (int i = 0; i < WM; ++i)
#pragma unroll
      for (int j = 0; j < WN; ++j)
        acc[i][j] = __builtin_amdgcn_mfma_f32_16x16x32_bf16(af[i], bfr[j], acc[i][j], 0, 0, 0);
    __syncthreads();
  }
  // D layout: col = lane&15, row = (lane>>4)*4 + r
#pragma unroll
  for (int i = 0; i < WM; ++i) {
#pragma unroll
    for (int j = 0; j < WN; ++j) {
      int col = bn + nb + j*16 + lr;
      if (col < N) {
#pragma unroll
        for (int r = 0; r < 4; ++r) {
          int row = bm + mb + i*16 + (lane>>4)*4 + r;
          size_t o = (size_t)row*N + col;
          C[o] = ACC ? (C[o] + acc[i][j][r]) : acc[i][j][r];
        }
      }
    }
  }
}

// ---- conv + silu + x_proj + dt_proj + scan phase 1, one block per 16-row chunk.
// 512 threads: thread e owns channel e. conv -> xv regs -> LDS bf16 tile -> MFMA
// (waves 0..2) -> dbc global + D/B LDS -> per-channel local scan (S, Q out).
__global__ __launch_bounds__(512) void k_cxps1(
    const float* __restrict__ xz, const float* __restrict__ cw, const float* __restrict__ cb,
    const unsigned short* __restrict__ wxp, const float* __restrict__ dtw,
    const float* __restrict__ dtb, const float* __restrict__ alog,
    float* __restrict__ xc, float* __restrict__ dbc,
    float* __restrict__ S, float* __restrict__ Q)
{
  constexpr int LDA = ED + 8;   // 520 ushorts per row
  __shared__ unsigned short As[CHUNK*LDA];
  __shared__ float Ds[CHUNK][DT_RANK];
  __shared__ float Bsh[CHUNK][NSTATE];
  const int tid = threadIdx.x;
  const int e = tid;
  const int c = blockIdx.x;
  const int t0 = c*CHUNK;
  // conv
  float cwv[KCONV];
#pragma unroll
  for (int k = 0; k < KCONV; ++k) cwv[k] = cw[e*KCONV+k];
  float cbv = cb[e];
  float w0=0.f, w1=0.f, w2=0.f;
  if (t0 > 0) {
    w0 = xz[(size_t)(t0-3)*(2*ED) + e];
    w1 = xz[(size_t)(t0-2)*(2*ED) + e];
    w2 = xz[(size_t)(t0-1)*(2*ED) + e];
  }
  float xv[CHUNK];
#pragma unroll
  for (int t = 0; t < CHUNK; ++t) {
    float cur = xz[(size_t)(t0+t)*(2*ED) + e];
    float v = siluf_(cbv + w0*cwv[0] + w1*cwv[1] + w2*cwv[2] + cur*cwv[3]);
    xv[t] = v;
    xc[(size_t)(t0+t)*ED + e] = v;
    w0=w1; w1=w2; w2=cur;
  }
  // pack pairs to LDS (even lanes write u32)
#pragma unroll
  for (int t = 0; t < CHUNK; ++t) {
    unsigned int us = f2bf(xv[t]);
    unsigned int other = (unsigned int)__shfl_down((int)us, 1);
    if ((tid & 1) == 0) *(unsigned int*)&As[t*LDA + e] = us | (other << 16);
  }
  __syncthreads();
  // x_proj MFMA: dbc[16 x 48] = A[16 x 512] @ wxp[48 x 512]^T ; waves 0..2
  const int w = tid >> 6, lane = tid & 63;
  const int lr = lane & 15, lk = (lane>>4)*8;
  if (w < 3) {
    f32x4 acc = {};
#pragma unroll
    for (int ks = 0; ks < ED/32; ++ks) {
      short8 af = *(const short8*)&As[lr*LDA + ks*32 + lk];
      short8 bf = *(const short8*)&wxp[(size_t)(w*16+lr)*ED + ks*32 + lk];
      acc = __builtin_amdgcn_mfma_f32_16x16x32_bf16(af, bf, acc, 0, 0, 0);
    }
#pragma unroll
    for (int r = 0; r < 4; ++r) {
      int row = (lane>>4)*4 + r;
      dbc[(size_t)(t0+row)*48 + w*16 + lr] = acc[r];
      if (w == 0) Ds[row][lr] = acc[r];
      else if (w == 1) Bsh[row][lr] = acc[r];
    }
  }
  __syncthreads();
  // scan phase 1 (dt_proj fused)
  float dtwv[DT_RANK];
#pragma unroll
  for (int r = 0; r < DT_RANK; ++r) dtwv[r] = dtw[e*DT_RANK+r];
  float dtbv = dtb[e];
  float A[NSTATE], h[NSTATE];
#pragma unroll
  for (int n = 0; n < NSTATE; ++n) { A[n] = -__expf(alog[e*NSTATE+n]); h[n] = 0.f; }
  float sd = 0.f;
#pragma unroll
  for (int t = 0; t < CHUNK; ++t) {
    float da = dtbv;
#pragma unroll
    for (int r = 0; r < DT_RANK; ++r) da += Ds[t][r]*dtwv[r];
    float d = softplusf_(da);
    sd += d;
    float dx = d*xv[t];
#pragma unroll
    for (int n = 0; n < NSTATE; ++n)
      h[n] = __expf(d*A[n])*h[n] + dx*Bsh[t][n];
  }
  S[(size_t)c*ED + e] = sd;
#pragma unroll
  for (int n = 0; n < NSTATE; ++n) Q[(size_t)(c*NSTATE+n)*ED + e] = h[n];
}

// Phase 2: segmented affine scan. 256 blocks x 256 thr; block = 32 channels x 8 segs.
// Each thread composes 32 chunks; LDS combine across 8 segs; replay writes Hin in-place.
__global__ __launch_bounds__(256) void k_scan2(
    const float* __restrict__ alog, const float* __restrict__ S, float* __restrict__ Q)
{
  __shared__ float Pl[8][32], Rl[8][32], Hs[8][32];
  const int tid = threadIdx.x;
  const int seg = tid >> 5, chl = tid & 31;
  const int ch = blockIdx.x*32 + chl;
  const int n = ch >> 9, e = ch & 511;
  const float a = -__expf(alog[e*NSTATE+n]);
  const int c0 = seg*32;
  float ev[32], qv[32];
#pragma unroll
  for (int k = 0; k < 32; ++k) ev[k] = S[(size_t)(c0+k)*ED + e];
#pragma unroll
  for (int k = 0; k < 32; ++k) qv[k] = Q[(size_t)((c0+k)*NSTATE+n)*ED + e];
#pragma unroll
  for (int k = 0; k < 32; ++k) ev[k] = __expf(a*ev[k]);
  float P = 1.f, R = 0.f;
#pragma unroll
  for (int k = 0; k < 32; ++k) { R = ev[k]*R + qv[k]; P *= ev[k]; }
  Pl[seg][chl] = P; Rl[seg][chl] = R;
  __syncthreads();
  if (tid < 32) {
    float hcur = 0.f;
#pragma unroll
    for (int s = 0; s < 8; ++s) { Hs[s][tid] = hcur; hcur = Pl[s][tid]*hcur + Rl[s][tid]; }
  }
  __syncthreads();
  float h = Hs[seg][chl];
#pragma unroll
  for (int k = 0; k < 32; ++k) {
    Q[(size_t)((c0+k)*NSTATE+n)*ED + e] = h;
    h = ev[k]*h + qv[k];
  }
}

// Phase 3: replay chunk with true Hin; fuse dt_proj, C-dot, D-skip, silu(z); bf16 y.
// 256 blocks x 512 threads, one block per chunk, thread e = channel.
__global__ __launch_bounds__(512) void k_scan3(
    const float* __restrict__ xc, const float* __restrict__ dbc,
    const float* __restrict__ dtw, const float* __restrict__ dtb,
    const float* __restrict__ alog, const float* __restrict__ Hin,
    const float* __restrict__ xz, const float* __restrict__ Dv,
    unsigned short* __restrict__ y)
{
  __shared__ float Ds[CHUNK][DT_RANK];
  __shared__ float Bsh[CHUNK][NSTATE];
  __shared__ float Cs[CHUNK][NSTATE];
  const int tid = threadIdx.x;
  const int e = tid;
  const int c = blockIdx.x;
  const int t0 = c*CHUNK;
  for (int i = tid; i < CHUNK*48; i += 512) {
    int t = i/48, col = i - t*48;
    float v = dbc[(size_t)(t0+t)*48 + col];
    if (col < DT_RANK) Ds[t][col] = v;
    else if (col < DT_RANK+NSTATE) Bsh[t][col-DT_RANK] = v;
    else Cs[t][col-DT_RANK-NSTATE] = v;
  }
  __syncthreads();
  float dtwv[DT_RANK];
#pragma unroll
  for (int r = 0; r < DT_RANK; ++r) dtwv[r] = dtw[e*DT_RANK+r];
  float dtbv = dtb[e];
  float x[CHUNK], z[CHUNK];
#pragma unroll
  for (int t = 0; t < CHUNK; ++t) x[t] = xc[(size_t)(t0+t)*ED + e];
#pragma unroll
  for (int t = 0; t < CHUNK; ++t) z[t] = xz[(size_t)(t0+t)*(2*ED) + ED + e];
  float A[NSTATE], h[NSTATE];
#pragma unroll
  for (int n = 0; n < NSTATE; ++n) {
    A[n] = -__expf(alog[e*NSTATE+n]);
    h[n] = Hin[(size_t)(c*NSTATE+n)*ED + e];
  }
  float dv = Dv[e];
#pragma unroll
  for (int t = 0; t < CHUNK; ++t) {
    float da = dtbv;
#pragma unroll
    for (int r = 0; r < DT_RANK; ++r) da += Ds[t][r]*dtwv[r];
    float d = softplusf_(da);
    float dx = d*x[t];
    float ysum = 0.f;
#pragma unroll
    for (int n = 0; n < NSTATE; ++n) {
      h[n] = __expf(d*A[n])*h[n] + dx*Bsh[t][n];
      ysum += h[n]*Cs[t][n];
    }
    y[(size_t)(t0+t)*ED + e] = f2bf((ysum + dv*x[t]) * siluf_(z[t]));
  }
}

// out[t] = tanh( h[t][:] . fc_out_w + fc_out_b ) — one wave per row
__global__ void k_fc_out(const float* __restrict__ h, const float* __restrict__ w,
                         const float* __restrict__ b, float* __restrict__ out){
  int wave = threadIdx.x >> 6, lane = threadIdx.x & 63;
  int row = blockIdx.x*4 + wave;
  const float4 hv = *(const float4*)&h[row*D_MODEL + lane*4];
  const float4 wv = *(const float4*)&w[lane*4];
  float s = hv.x*wv.x + hv.y*wv.y + hv.z*wv.z + hv.w*wv.w;
#pragma unroll
  for (int m = 32; m; m >>= 1) s += __shfl_xor(s, m);
  if (lane == 0) out[row] = tanhf(s + b[0]);
}

extern "C" void kernel_launch(void* const* d_in, const int* in_sizes, int n_in,
                              void* d_out, int out_size, void* d_ws, size_t ws_size,
                              hipStream_t stream){
  const float* x    = (const float*)d_in[0];
  const float* fiw  = (const float*)d_in[1];
  const float* fib  = (const float*)d_in[2];
  const float* fow  = (const float*)d_in[3];
  const float* fob  = (const float*)d_in[4];
  const float* nw   = (const float*)d_in[5];
  const float* ipw  = (const float*)d_in[6];
  const float* cw   = (const float*)d_in[7];
  const float* cb   = (const float*)d_in[8];
  const float* xpw  = (const float*)d_in[9];
  const float* dtw  = (const float*)d_in[10];
  const float* dtb  = (const float*)d_in[11];
  const float* alog = (const float*)d_in[12];
  const float* Dv   = (const float*)d_in[13];
  const float* opw  = (const float*)d_in[14];

  float* W = (float*)d_ws;
  float* h   = W;                                   // L*256
  float* xz  = h   + (size_t)LSEQ*D_MODEL;          // L*1024
  float* xc  = xz  + (size_t)LSEQ*2*ED;             // L*512
  float* dbc = xc  + (size_t)LSEQ*ED;               // L*48
  float* S   = dbc + (size_t)LSEQ*48;               // 256*512
  float* Q   = S   + (size_t)NCHUNK*ED;             // 256*16*512 (Hin in-place)
  unsigned short* yb  = (unsigned short*)(Q + (size_t)NCHUNK*NSTATE*ED); // L*512 bf16
  unsigned short* wip = yb  + (size_t)LSEQ*ED;      // 2*1024*256
  unsigned short* wxp = wip + (size_t)2*2*ED*D_MODEL; // 2*48*512
  unsigned short* wop = wxp + (size_t)2*48*ED;      // 2*256*512

  k_prep<<<2048 + LSEQ, 256, 0, stream>>>(x, fiw, fib, ipw, xpw, opw, h, wip, wxp, wop);

  for (int l = 0; l < 2; ++l) {
    const unsigned short* wip_l = wip + (size_t)l*2*ED*D_MODEL;
    const unsigned short* wxp_l = wxp + (size_t)l*48*ED;
    const unsigned short* wop_l = wop + (size_t)l*D_MODEL*ED;
    const float* nw_l   = nw   + l*D_MODEL;
    const float* cw_l   = cw   + l*ED*KCONV;
    const float* cb_l   = cb   + l*ED;
    const float* dtw_l  = dtw  + l*ED*DT_RANK;
    const float* dtb_l  = dtb  + l*ED;
    const float* alog_l = alog + l*ED*NSTATE;
    const float* D_l    = Dv   + l*ED;

    k_gemm_mfma<4,4,true,false,false><<<dim3(LSEQ/128, (2*ED)/128), 256, 0, stream>>>(
        h, wip_l, xz, LSEQ, 2*ED, D_MODEL, nw_l);
    k_cxps1<<<NCHUNK, 512, 0, stream>>>(xz, cw_l, cb_l, wxp_l, dtw_l, dtb_l, alog_l,
                                        xc, dbc, S, Q);
    k_scan2<<<NCHUNK, 256, 0, stream>>>(alog_l, S, Q);
    k_scan3<<<NCHUNK, 512, 0, stream>>>(xc, dbc, dtw_l, dtb_l, alog_l, Q, xz, D_l, yb);
    k_gemm_mfma<2,2,false,true,true><<<dim3(LSEQ/64, D_MODEL/64), 256, 0, stream>>>(
        yb, wop_l, h, LSEQ, D_MODEL, ED, nullptr);
  }

  k_fc_out<<<LSEQ/4, 256, 0, stream>>>(h, fow, fob, (float*)d_out);
}